// Round 21
// baseline (93.551 us; speedup 1.0000x reference)
//
#include <hip/hip_runtime.h>
#include <hip/hip_bf16.h>
#include <stdint.h>

typedef __attribute__((ext_vector_type(8))) short short8;
typedef __attribute__((ext_vector_type(4))) float f32x4;
typedef __attribute__((ext_vector_type(16))) float f32x16;

#define MFMA16(a, b, c) __builtin_amdgcn_mfma_f32_16x16x32_bf16(a, b, c, 0, 0, 0)
#define MFMA32(a, b, c) __builtin_amdgcn_mfma_f32_32x32x16_bf16(a, b, c, 0, 0, 0)

__device__ __forceinline__ unsigned short f2bf_u(float f) {
  union { float f; uint32_t u; } x; x.f = f;
  uint32_t r = (x.u + 0x7fffu + ((x.u >> 16) & 1u)) >> 16;
  return (unsigned short)r;
}
__device__ __forceinline__ short f2bf(float f) { return (short)f2bf_u(f); }

__device__ __forceinline__ uint32_t pack_bf2(float lo, float hi) {
  __hip_bfloat162 h = __float22bfloat162_rn(make_float2(lo, hi));  // v_cvt_pk_bf16_f32
  union { __hip_bfloat162 h; uint32_t u; } c; c.h = h;
  return c.u;
}

// hw exp2 via builtin: single v_exp_f32, hazards handled by codegen.
__device__ __forceinline__ float fexp2(float x) {
  return __builtin_amdgcn_exp2f(x);
}

// async global->LDS, 16B per lane. dest = wave-uniform base + lane*16.
__device__ __forceinline__ void gload_lds16(const void* g, void* lds) {
  __builtin_amdgcn_global_load_lds(
      (const __attribute__((address_space(1))) uint32_t*)(uintptr_t)g,
      (__attribute__((address_space(3))) uint32_t*)(uintptr_t)lds,
      16, 0, 0);
}

// ------- fused pre-pass: X fp32->bf16 convert + all W transposes, one launch -------
__global__ __launch_bounds__(256) void prepass_kernel(
    const float* __restrict__ X, const float* __restrict__ Wq,
    const float* __restrict__ Wk, const float* __restrict__ Wv,
    const float* __restrict__ Wo,
    short* __restrict__ XB, short* __restrict__ WTQKV, short* __restrict__ WOT) {
  __shared__ float tile[32][33];
  int bid = blockIdx.x;
  if (bid < 4096) {
    int i = bid * 256 + threadIdx.x;
    float4 v = reinterpret_cast<const float4*>(X)[i];
    short4 o;
    o.x = f2bf(v.x); o.y = f2bf(v.y); o.z = f2bf(v.z); o.w = f2bf(v.w);
    reinterpret_cast<short4*>(XB)[i] = o;
    return;
  }
  bid -= 4096;
  int bx = bid & 31, yb = bid >> 5;     // bx: k-tile, yb: 0..95
  const float* src; short* dst; int N; int yy;
  if (yb < 32)      { src = Wq; dst = WTQKV;                       N = 1024; yy = yb; }
  else if (yb < 48) { src = Wk; dst = WTQKV + (size_t)1024 * 1024; N = 512;  yy = yb - 32; }
  else if (yb < 64) { src = Wv; dst = WTQKV + (size_t)1536 * 1024; N = 512;  yy = yb - 48; }
  else              { src = Wo; dst = WOT;                         N = 1024; yy = yb - 64; }
  int k0 = bx * 32, n0 = yy * 32;
  int tx = threadIdx.x & 31, ty = threadIdx.x >> 5;  // (32,8)
#pragma unroll
  for (int i = 0; i < 4; ++i)
    tile[ty + 8 * i][tx] = src[(size_t)(k0 + ty + 8 * i) * N + n0 + tx];
  __syncthreads();
#pragma unroll
  for (int i = 0; i < 4; ++i)
    dst[(size_t)(n0 + ty + 8 * i) * 1024 + k0 + tx] = f2bf(tile[tx][ty + 8 * i]);
}

// -------- GEMM1 fused: QKV = XB @ WTQKV^T, + RMSNorm + 2D RoPE + layouts --------
// 128x128 tile, BK=32 dbuf, counted-vmcnt pipeline.
__global__ __launch_bounds__(256) void gemm_qkv_fused(
    const short* __restrict__ A, const short* __restrict__ BT,
    const float* __restrict__ qg, const float* __restrict__ kg,
    const int* __restrict__ pos,
    short* __restrict__ Qp, short* __restrict__ Kp, short* __restrict__ Vt) {
  const int K = 1024;
  __shared__ short As[2][128 * 32];
  __shared__ short Bs[2][128 * 32];
  int wg = blockIdx.x + gridDim.x * blockIdx.y;      // nwg = 512
  int lid = (wg & 7) * 64 + (wg >> 3);               // XCD-contiguous
  int m0 = (lid & 31) * 128, n0 = (lid >> 5) * 128;
  int t = threadIdx.x;
  int w = t >> 6, lane = t & 63;
  int wr = w >> 1, wc = w & 1;
  int lr = lane & 15, lg = lane >> 4;

  f32x4 acc[4][4] = {};

  auto STAGE = [&](int buf, int k0) {
#pragma unroll
    for (int i = 0; i < 2; ++i) {
      int q = t + 256 * i;                 // 0..511 chunks each matrix
      int row = q >> 2, c = q & 3;
      gload_lds16(A + (size_t)(m0 + row) * K + k0 + c * 8, &As[buf][q * 8]);
      gload_lds16(BT + (size_t)(n0 + row) * K + k0 + c * 8, &Bs[buf][q * 8]);
    }
  };

  auto COMPUTE = [&](int buf) {
    short8 af[4], bf[4];
#pragma unroll
    for (int mi = 0; mi < 4; ++mi)
      af[mi] = *(const short8*)&As[buf][(wr * 64 + mi * 16 + lr) * 32 + lg * 8];
#pragma unroll
    for (int ni = 0; ni < 4; ++ni)
      bf[ni] = *(const short8*)&Bs[buf][(wc * 64 + ni * 16 + lr) * 32 + lg * 8];
    __builtin_amdgcn_s_setprio(1);
#pragma unroll
    for (int mi = 0; mi < 4; ++mi)
#pragma unroll
      for (int ni = 0; ni < 4; ++ni)
        acc[mi][ni] = MFMA16(af[mi], bf[ni], acc[mi][ni]);
    __builtin_amdgcn_s_setprio(0);
  };

  STAGE(0, 0);
  int cur = 0;
  for (int kt = 0; kt < 31; ++kt) {
    STAGE(cur ^ 1, (kt + 1) * 32);
    asm volatile("s_waitcnt vmcnt(4)" ::: "memory");   // tile kt staged; kt+1 in flight
    __builtin_amdgcn_s_barrier();
    __builtin_amdgcn_sched_barrier(0);
    COMPUTE(cur);
    __builtin_amdgcn_sched_barrier(0);
    __builtin_amdgcn_s_barrier();                      // all reads done before overwrite
    cur ^= 1;
  }
  asm volatile("s_waitcnt vmcnt(0)" ::: "memory");
  __builtin_amdgcn_s_barrier();
  COMPUTE(cur);

  // ---- fused epilogue ----
  int g = (n0 >> 6) + wc;        // 0..31: head-vector group. <16 Q, <24 K, else V
  int row0 = m0 + wr * 64;
  const int2* posv = (const int2*)pos;

  if (g < 24) {
    const float* gsrc = (g < 16) ? qg : kg;
    short* dst = (g < 16) ? Qp : Kp;
    int nh = (g < 16) ? 16 : 8;
    int h = (g < 16) ? g : g - 16;
    float gscale = (g < 16) ? 1.4426950408889634f : 1.0f;   // Q *= log2(e)
    float gam[4];
#pragma unroll
    for (int ni = 0; ni < 4; ++ni) gam[ni] = (1.0f + gsrc[ni * 16 + lr]) * gscale;
    float invf = exp2f((float)lr * -0.8304820237218405f);  // 10000^(-lr/16)
#pragma unroll
    for (int mi = 0; mi < 4; ++mi) {
      f32x4 ss = acc[mi][0] * acc[mi][0];
#pragma unroll
      for (int ni = 1; ni < 4; ++ni) ss += acc[mi][ni] * acc[mi][ni];
#pragma unroll
      for (int m2 = 1; m2 < 16; m2 <<= 1)
#pragma unroll
        for (int r = 0; r < 4; ++r) ss[r] += __shfl_xor(ss[r], m2);
#pragma unroll
      for (int r = 0; r < 4; ++r) {
        int row = row0 + mi * 16 + lg * 4 + r;
        float inv = rsqrtf(ss[r] * 0.015625f + 1e-6f);
        float v0 = acc[mi][0][r] * inv * gam[0];
        float v1 = acc[mi][1][r] * inv * gam[1];
        float v2 = acc[mi][2][r] * inv * gam[2];
        float v3 = acc[mi][3][r] * inv * gam[3];
        int2 pp = posv[row];
        float sx, cx, sy, cy;
        __sincosf((float)pp.x * invf, &sx, &cx);
        __sincosf((float)pp.y * invf, &sy, &cy);
        float o0 = v0 * cx - v1 * sx, o1 = v1 * cx + v0 * sx;
        float o2 = v2 * cy - v3 * sy, o3 = v3 * cy + v2 * sy;
        int s = row & 1023, bb = row >> 10;
        short* base = dst + ((size_t)((bb * nh + h) * 1024 + s)) * 64;
        base[lr]      = f2bf(o0);
        base[lr + 16] = f2bf(o1);
        base[lr + 32] = f2bf(o2);
        base[lr + 48] = f2bf(o3);
      }
    }
  } else {
    int hk = g - 24;
#pragma unroll
    for (int mi = 0; mi < 4; ++mi) {
      f32x4 ss = acc[mi][0] * acc[mi][0];
#pragma unroll
      for (int ni = 1; ni < 4; ++ni) ss += acc[mi][ni] * acc[mi][ni];
#pragma unroll
      for (int m2 = 1; m2 < 16; m2 <<= 1)
#pragma unroll
        for (int r = 0; r < 4; ++r) ss[r] += __shfl_xor(ss[r], m2);
      f32x4 inv;
#pragma unroll
      for (int r = 0; r < 4; ++r) inv[r] = rsqrtf(ss[r] * 0.015625f + 1e-6f);
      int row = row0 + mi * 16 + lg * 4;
      int s0 = row & 1023, bb = row >> 10;
      int kv = s0 & 63, c = kv >> 3, hb = (kv >> 2) & 1;
      int sp = (s0 & ~63) | (((c & 6) | hb) << 3) | ((c & 1) << 2);
#pragma unroll
      for (int ni = 0; ni < 4; ++ni) {
        short4 sv;
        sv.x = f2bf(acc[mi][ni][0] * inv[0]);
        sv.y = f2bf(acc[mi][ni][1] * inv[1]);
        sv.z = f2bf(acc[mi][ni][2] * inv[2]);
        sv.w = f2bf(acc[mi][ni][3] * inv[3]);
        int d = ni * 16 + lr;
        *(short4*)&Vt[((size_t)((bb * 8 + hk) * 64 + d)) * 1024 + sp] = sv;
      }
    }
  }
}

// ------- 128x64-tile GEMM (out-proj), BK=32 dbuf, counted-vmcnt pipeline -------
__global__ __launch_bounds__(256) void gemm_bf16_bn64(
    const short* __restrict__ A, const short* __restrict__ BT,
    float* __restrict__ C, int M, int N, int K) {
  __shared__ short As[2][128 * 32];
  __shared__ short Bs[2][64 * 32];
  int wg = blockIdx.x + gridDim.x * blockIdx.y;      // nwg = 512
  int lid = (wg & 7) * 64 + (wg >> 3);
  int m0 = (lid & 31) * 128, n0 = (lid >> 5) * 64;
  int t = threadIdx.x;
  int w = t >> 6, lane = t & 63;
  int lr = lane & 15, lg = lane >> 4;

  f32x4 acc[2][4] = {};

  auto STAGE = [&](int buf, int k0) {
#pragma unroll
    for (int i = 0; i < 2; ++i) {
      int q = t + 256 * i;
      int row = q >> 2, c = q & 3;
      gload_lds16(A + (size_t)(m0 + row) * K + k0 + c * 8, &As[buf][q * 8]);
    }
    {
      int row = t >> 2, c = t & 3;       // 256 B-chunks
      gload_lds16(BT + (size_t)(n0 + row) * K + k0 + c * 8, &Bs[buf][t * 8]);
    }
  };

  auto COMPUTE = [&](int buf) {
    short8 af[2], bf[4];
#pragma unroll
    for (int mi = 0; mi < 2; ++mi)
      af[mi] = *(const short8*)&As[buf][(w * 32 + mi * 16 + lr) * 32 + lg * 8];
#pragma unroll
    for (int ni = 0; ni < 4; ++ni)
      bf[ni] = *(const short8*)&Bs[buf][(ni * 16 + lr) * 32 + lg * 8];
    __builtin_amdgcn_s_setprio(1);
#pragma unroll
    for (int mi = 0; mi < 2; ++mi)
#pragma unroll
      for (int ni = 0; ni < 4; ++ni)
        acc[mi][ni] = MFMA16(af[mi], bf[ni], acc[mi][ni]);
    __builtin_amdgcn_s_setprio(0);
  };

  STAGE(0, 0);
  int cur = 0;
  for (int kt = 0; kt < 31; ++kt) {
    STAGE(cur ^ 1, (kt + 1) * 32);
    asm volatile("s_waitcnt vmcnt(3)" ::: "memory");   // tile kt staged; kt+1 in flight
    __builtin_amdgcn_s_barrier();
    __builtin_amdgcn_sched_barrier(0);
    COMPUTE(cur);
    __builtin_amdgcn_sched_barrier(0);
    __builtin_amdgcn_s_barrier();
    cur ^= 1;
  }
  asm volatile("s_waitcnt vmcnt(0)" ::: "memory");
  __builtin_amdgcn_s_barrier();
  COMPUTE(cur);

#pragma unroll
  for (int mi = 0; mi < 2; ++mi)
#pragma unroll
    for (int ni = 0; ni < 4; ++ni) {
      int row = m0 + w * 32 + mi * 16 + lg * 4;
      int col = n0 + ni * 16 + lr;
#pragma unroll
      for (int r = 0; r < 4; ++r)
        C[(size_t)(row + r) * N + col] = acc[mi][ni][r];
    }
}

// ------- attention v17: BARRIER-FREE wave-private pipeline -------
// grid 2048 = B*H*(S/32). Block = 32 q rows, 4 waves; wave w owns kv quarter
// [w*256,+256) in 8 tiles of 32 kv AND a private 16KB LDS region (2buf x (4K+4V)).
// No wave reads another wave's buffers -> ZERO s_barriers in the main loop; only
// per-wave counted vmcnt(8). Waves fully decoupled (no lockstep). LDS 64KB ->
// 2 blocks/CU = 8 waves/CU (same occupancy as v14; isolates the barrier variable).
// 4 partials merged via LDS (pure sums; no-max softmax).
__global__ __launch_bounds__(256, 2) void attn_kernel(
    const short* __restrict__ Qp, const short* __restrict__ Kp,
    const short* __restrict__ Vt, short* __restrict__ attn) {
  __shared__ short smem[4][2][4096];    // [wave][buf][K 2048 | V 2048] = 64KB
  __shared__ float lsl[3][32][2];       // w>0 lsum partials [w-1][l31][hh]
  int wg = blockIdx.x;
  int xcd = wg & 7, slot = wg >> 3;        // 0..255
  int group = xcd * 8 + (slot >> 5);       // 0..63 = (b,h); 8 groups/XCD
  int qb = slot & 31;
  int b = group >> 4, h = group & 15;
  int hk = h >> 1;
  int t = threadIdx.x;                     // 0..255
  int w = t >> 6, lane = t & 63;
  int l31 = lane & 31, hh = lane >> 5;
  int xr = l31 & 7;
  int q0 = qb * 32;

  const short* Qb = Qp + ((size_t)(b * 16 + h) * 1024) * 64;
  const short* Kb = Kp + ((size_t)(b * 8 + hk) * 1024) * 64;
  const short* Vb = Vt + ((size_t)(b * 8 + hk) * 64) * 1024;

  short8 qf[4];
#pragma unroll
  for (int dk = 0; dk < 4; ++dk)
    qf[dk] = *(const short8*)&Qb[(q0 + l31) * 64 + dk * 16 + hh * 8];

  f32x16 acc[2] = {};   // [db2]: out^T[d=db2*32+(r&3)+8*(r>>2)+4hh][q=q0+l31]
  f32x4 lsumv = {};

  auto STAGE = [&](int buf, int kt) {
    int kv0 = w * 256 + kt * 32;
    short* ksb = &smem[w][buf][0];
    short* vsb = &smem[w][buf][2048];
    // K tile: 32 kv x 64 d = 256 chunks / 64 lanes = 4 each (8/row, XOR kv&7)
#pragma unroll
    for (int i = 0; i < 4; ++i) {
      int c = i * 64 + lane;
      int kv = c >> 3, cd = c & 7, cs = cd ^ (kv & 7);
      gload_lds16(Kb + (size_t)(kv0 + kv) * 64 + cs * 8, &ksb[c * 8]);
    }
    // V tile: 64 d x 32 kv = 256 chunks (4/row, XOR d&3)
#pragma unroll
    for (int i = 0; i < 4; ++i) {
      int c = i * 64 + lane;
      int d = c >> 2, bi = c & 3, bs = bi ^ (d & 3);
      gload_lds16(Vb + (size_t)d * 1024 + kv0 + bs * 8, &vsb[c * 8]);
    }
  };

  auto COMPUTE = [&](int buf) {
    const short* ksb = &smem[w][buf][0];
    const short* vsb = &smem[w][buf][2048];
    short8 kf[4];
#pragma unroll
    for (int dk = 0; dk < 4; ++dk)
      kf[dk] = *(const short8*)&ksb[l31 * 64 + ((dk * 2 + hh) ^ xr) * 8];
    f32x16 sv = {};
    __builtin_amdgcn_s_setprio(1);
#pragma unroll
    for (int dk = 0; dk < 4; ++dk) sv = MFMA32(kf[dk], qf[dk], sv);
    __builtin_amdgcn_s_setprio(0);
    short8 vf[4];
#pragma unroll
    for (int kvc = 0; kvc < 2; ++kvc)
#pragma unroll
      for (int db2 = 0; db2 < 2; ++db2)
        vf[kvc * 2 + db2] = *(const short8*)
            &vsb[(db2 * 32 + l31) * 32 + (((kvc * 2 + hh) ^ (l31 & 3))) * 8];
    float p[16];
#pragma unroll
    for (int r = 0; r < 16; ++r) p[r] = fexp2(sv[r]);
#pragma unroll
    for (int r = 0; r < 16; r += 4) {
      lsumv[0] += p[r]; lsumv[1] += p[r + 1];
      lsumv[2] += p[r + 2]; lsumv[3] += p[r + 3];
    }
    uint32_t pk8[8];
#pragma unroll
    for (int j = 0; j < 8; ++j) pk8[j] = pack_bf2(p[2 * j], p[2 * j + 1]);
#pragma unroll
    for (int kvc = 0; kvc < 2; ++kvc) {
      union { uint32_t u[4]; short8 s; } pb;
#pragma unroll
      for (int j = 0; j < 4; ++j) pb.u[j] = pk8[kvc * 4 + j];
      __builtin_amdgcn_s_setprio(1);
#pragma unroll
      for (int db2 = 0; db2 < 2; ++db2)
        acc[db2] = MFMA32(vf[kvc * 2 + db2], pb.s, acc[db2]);
      __builtin_amdgcn_s_setprio(0);
    }
  };

  STAGE(0, 0);
  int cur = 0;
  for (int kt = 0; kt < 7; ++kt) {
    STAGE(cur ^ 1, kt + 1);
    asm volatile("s_waitcnt vmcnt(8)" ::: "memory");   // own tile kt ready; kt+1 in flight
    __builtin_amdgcn_sched_barrier(0);
    COMPUTE(cur);                                      // private region: no barrier needed
    cur ^= 1;
  }
  asm volatile("s_waitcnt vmcnt(0)" ::: "memory");
  __builtin_amdgcn_sched_barrier(0);
  COMPUTE(cur);

  // ---- merge 4 kv-quarter partials (pure sums; no-max softmax) ----
  float lsum = (lsumv[0] + lsumv[1]) + (lsumv[2] + lsumv[3]);
  __syncthreads();                      // all waves done with their regions
  float* accl = (float*)smem;           // [w-1][l31][hh][36] floats = 27.6KB < 64KB
  float* ab = accl + ((((w - 1) * 32 + l31) * 2 + hh) * 36);
  if (w > 0) {
#pragma unroll
    for (int db2 = 0; db2 < 2; ++db2)
#pragma unroll
      for (int j4 = 0; j4 < 4; ++j4) {
        f32x4 sv4;
        sv4[0] = acc[db2][j4 * 4];
        sv4[1] = acc[db2][j4 * 4 + 1];
        sv4[2] = acc[db2][j4 * 4 + 2];
        sv4[3] = acc[db2][j4 * 4 + 3];
        *(f32x4*)&ab[db2 * 16 + j4 * 4] = sv4;
      }
    lsl[w - 1][l31][hh] = lsum;
  }
  __syncthreads();
  if (w == 0) {
#pragma unroll
    for (int s2 = 0; s2 < 3; ++s2) {
      const float* rb = accl + (((s2 * 32 + l31) * 2 + hh) * 36);
#pragma unroll
      for (int db2 = 0; db2 < 2; ++db2)
#pragma unroll
        for (int j4 = 0; j4 < 4; ++j4) {
          f32x4 o = *(const f32x4*)&rb[db2 * 16 + j4 * 4];
          acc[db2][j4 * 4]     += o[0];
          acc[db2][j4 * 4 + 1] += o[1];
          acc[db2][j4 * 4 + 2] += o[2];
          acc[db2][j4 * 4 + 3] += o[3];
        }
    }
    lsum += lsl[0][l31][hh] + lsl[1][l31][hh] + lsl[2][l31][hh];
    lsum += __shfl_xor(lsum, 32);
    float inv = 1.0f / lsum;
    short* orow = attn + ((size_t)(b * 1024 + q0 + l31)) * 1024 + h * 64;
#pragma unroll
    for (int db2 = 0; db2 < 2; ++db2)
#pragma unroll
      for (int g2 = 0; g2 < 4; ++g2) {
        int d0 = db2 * 32 + g2 * 8 + 4 * hh;
        uint32_t w0 = pack_bf2(acc[db2][g2 * 4 + 0] * inv, acc[db2][g2 * 4 + 1] * inv);
        uint32_t w1 = pack_bf2(acc[db2][g2 * 4 + 2] * inv, acc[db2][g2 * 4 + 3] * inv);
        *(uint2*)&orow[d0] = make_uint2(w0, w1);
      }
  }
}

extern "C" void kernel_launch(void* const* d_in, const int* in_sizes, int n_in,
                              void* d_out, int out_size, void* d_ws, size_t ws_size,
                              hipStream_t stream) {
  const float* X  = (const float*)d_in[0];
  const float* Wq = (const float*)d_in[1];
  const float* Wk = (const float*)d_in[2];
  const float* Wv = (const float*)d_in[3];
  const float* Wo = (const float*)d_in[4];
  const float* qg = (const float*)d_in[5];
  const float* kg = (const float*)d_in[6];
  const int* pos  = (const int*)d_in[7];
  float* out = (float*)d_out;

  char* ws = (char*)d_ws;
  short* XB    = (short*)(ws);                       // 8 MB  X bf16
  short* WTQKV = (short*)(ws + ((size_t)8 << 20));   // 4 MB  [Wq^T;Wk^T;Wv^T]
  short* WOT   = (short*)(ws + ((size_t)12 << 20));  // 2 MB  Wo^T
  short* QP    = (short*)(ws + ((size_t)14 << 20));  // 8 MB
  short* KP    = (short*)(ws + ((size_t)22 << 20));  // 4 MB
  short* VT    = (short*)(ws + ((size_t)26 << 20));  // 4 MB
  short* ATT   = (short*)(ws + ((size_t)30 << 20));  // 8 MB -> 38 MB total

  prepass_kernel<<<4096 + 3072, 256, 0, stream>>>(X, Wq, Wk, Wv, Wo, XB, WTQKV, WOT);
  gemm_qkv_fused<<<dim3(32, 16), 256, 0, stream>>>(XB, WTQKV, qg, kg, pos, QP, KP, VT);
  attn_kernel<<<2048, 256, 0, stream>>>(QP, KP, VT, ATT);
  gemm_bf16_bn64<<<dim3(32, 16), 256, 0, stream>>>(ATT, WOT, out, 4096, 1024, 1024);
}

// Round 22
// 85.577 us; speedup vs baseline: 1.0932x; 1.0932x over previous
//
#include <hip/hip_runtime.h>
#include <hip/hip_bf16.h>
#include <stdint.h>

typedef __attribute__((ext_vector_type(8))) short short8;
typedef __attribute__((ext_vector_type(4))) float f32x4;
typedef __attribute__((ext_vector_type(16))) float f32x16;

#define MFMA16(a, b, c) __builtin_amdgcn_mfma_f32_16x16x32_bf16(a, b, c, 0, 0, 0)
#define MFMA32(a, b, c) __builtin_amdgcn_mfma_f32_32x32x16_bf16(a, b, c, 0, 0, 0)

__device__ __forceinline__ unsigned short f2bf_u(float f) {
  union { float f; uint32_t u; } x; x.f = f;
  uint32_t r = (x.u + 0x7fffu + ((x.u >> 16) & 1u)) >> 16;
  return (unsigned short)r;
}
__device__ __forceinline__ short f2bf(float f) { return (short)f2bf_u(f); }

__device__ __forceinline__ uint32_t pack_bf2(float lo, float hi) {
  __hip_bfloat162 h = __float22bfloat162_rn(make_float2(lo, hi));  // v_cvt_pk_bf16_f32
  union { __hip_bfloat162 h; uint32_t u; } c; c.h = h;
  return c.u;
}

// hw exp2 via builtin: single v_exp_f32, hazards handled by codegen.
__device__ __forceinline__ float fexp2(float x) {
  return __builtin_amdgcn_exp2f(x);
}

// async global->LDS, 16B per lane. dest = wave-uniform base + lane*16.
__device__ __forceinline__ void gload_lds16(const void* g, void* lds) {
  __builtin_amdgcn_global_load_lds(
      (const __attribute__((address_space(1))) uint32_t*)(uintptr_t)g,
      (__attribute__((address_space(3))) uint32_t*)(uintptr_t)lds,
      16, 0, 0);
}

// ------- fused pre-pass: X fp32->bf16 convert + all W transposes, one launch -------
__global__ __launch_bounds__(256) void prepass_kernel(
    const float* __restrict__ X, const float* __restrict__ Wq,
    const float* __restrict__ Wk, const float* __restrict__ Wv,
    const float* __restrict__ Wo,
    short* __restrict__ XB, short* __restrict__ WTQKV, short* __restrict__ WOT) {
  __shared__ float tile[32][33];
  int bid = blockIdx.x;
  if (bid < 4096) {
    int i = bid * 256 + threadIdx.x;
    float4 v = reinterpret_cast<const float4*>(X)[i];
    short4 o;
    o.x = f2bf(v.x); o.y = f2bf(v.y); o.z = f2bf(v.z); o.w = f2bf(v.w);
    reinterpret_cast<short4*>(XB)[i] = o;
    return;
  }
  bid -= 4096;
  int bx = bid & 31, yb = bid >> 5;     // bx: k-tile, yb: 0..95
  const float* src; short* dst; int N; int yy;
  if (yb < 32)      { src = Wq; dst = WTQKV;                       N = 1024; yy = yb; }
  else if (yb < 48) { src = Wk; dst = WTQKV + (size_t)1024 * 1024; N = 512;  yy = yb - 32; }
  else if (yb < 64) { src = Wv; dst = WTQKV + (size_t)1536 * 1024; N = 512;  yy = yb - 48; }
  else              { src = Wo; dst = WOT;                         N = 1024; yy = yb - 64; }
  int k0 = bx * 32, n0 = yy * 32;
  int tx = threadIdx.x & 31, ty = threadIdx.x >> 5;  // (32,8)
#pragma unroll
  for (int i = 0; i < 4; ++i)
    tile[ty + 8 * i][tx] = src[(size_t)(k0 + ty + 8 * i) * N + n0 + tx];
  __syncthreads();
#pragma unroll
  for (int i = 0; i < 4; ++i)
    dst[(size_t)(n0 + ty + 8 * i) * 1024 + k0 + tx] = f2bf(tile[tx][ty + 8 * i]);
}

// -------- GEMM1 fused: QKV = XB @ WTQKV^T, + RMSNorm + 2D RoPE + layouts --------
// 128x128 tile, BK=32 dbuf, counted-vmcnt pipeline.
__global__ __launch_bounds__(256) void gemm_qkv_fused(
    const short* __restrict__ A, const short* __restrict__ BT,
    const float* __restrict__ qg, const float* __restrict__ kg,
    const int* __restrict__ pos,
    short* __restrict__ Qp, short* __restrict__ Kp, short* __restrict__ Vt) {
  const int K = 1024;
  __shared__ short As[2][128 * 32];
  __shared__ short Bs[2][128 * 32];
  int wg = blockIdx.x + gridDim.x * blockIdx.y;      // nwg = 512
  int lid = (wg & 7) * 64 + (wg >> 3);               // XCD-contiguous
  int m0 = (lid & 31) * 128, n0 = (lid >> 5) * 128;
  int t = threadIdx.x;
  int w = t >> 6, lane = t & 63;
  int wr = w >> 1, wc = w & 1;
  int lr = lane & 15, lg = lane >> 4;

  f32x4 acc[4][4] = {};

  auto STAGE = [&](int buf, int k0) {
#pragma unroll
    for (int i = 0; i < 2; ++i) {
      int q = t + 256 * i;                 // 0..511 chunks each matrix
      int row = q >> 2, c = q & 3;
      gload_lds16(A + (size_t)(m0 + row) * K + k0 + c * 8, &As[buf][q * 8]);
      gload_lds16(BT + (size_t)(n0 + row) * K + k0 + c * 8, &Bs[buf][q * 8]);
    }
  };

  auto COMPUTE = [&](int buf) {
    short8 af[4], bf[4];
#pragma unroll
    for (int mi = 0; mi < 4; ++mi)
      af[mi] = *(const short8*)&As[buf][(wr * 64 + mi * 16 + lr) * 32 + lg * 8];
#pragma unroll
    for (int ni = 0; ni < 4; ++ni)
      bf[ni] = *(const short8*)&Bs[buf][(wc * 64 + ni * 16 + lr) * 32 + lg * 8];
    __builtin_amdgcn_s_setprio(1);
#pragma unroll
    for (int mi = 0; mi < 4; ++mi)
#pragma unroll
      for (int ni = 0; ni < 4; ++ni)
        acc[mi][ni] = MFMA16(af[mi], bf[ni], acc[mi][ni]);
    __builtin_amdgcn_s_setprio(0);
  };

  STAGE(0, 0);
  int cur = 0;
  for (int kt = 0; kt < 31; ++kt) {
    STAGE(cur ^ 1, (kt + 1) * 32);
    asm volatile("s_waitcnt vmcnt(4)" ::: "memory");   // tile kt staged; kt+1 in flight
    __builtin_amdgcn_s_barrier();
    __builtin_amdgcn_sched_barrier(0);
    COMPUTE(cur);
    __builtin_amdgcn_sched_barrier(0);
    __builtin_amdgcn_s_barrier();                      // all reads done before overwrite
    cur ^= 1;
  }
  asm volatile("s_waitcnt vmcnt(0)" ::: "memory");
  __builtin_amdgcn_s_barrier();
  COMPUTE(cur);

  // ---- fused epilogue ----
  int g = (n0 >> 6) + wc;        // 0..31: head-vector group. <16 Q, <24 K, else V
  int row0 = m0 + wr * 64;
  const int2* posv = (const int2*)pos;

  if (g < 24) {
    const float* gsrc = (g < 16) ? qg : kg;
    short* dst = (g < 16) ? Qp : Kp;
    int nh = (g < 16) ? 16 : 8;
    int h = (g < 16) ? g : g - 16;
    float gscale = (g < 16) ? 1.4426950408889634f : 1.0f;   // Q *= log2(e)
    float gam[4];
#pragma unroll
    for (int ni = 0; ni < 4; ++ni) gam[ni] = (1.0f + gsrc[ni * 16 + lr]) * gscale;
    float invf = exp2f((float)lr * -0.8304820237218405f);  // 10000^(-lr/16)
#pragma unroll
    for (int mi = 0; mi < 4; ++mi) {
      f32x4 ss = acc[mi][0] * acc[mi][0];
#pragma unroll
      for (int ni = 1; ni < 4; ++ni) ss += acc[mi][ni] * acc[mi][ni];
#pragma unroll
      for (int m2 = 1; m2 < 16; m2 <<= 1)
#pragma unroll
        for (int r = 0; r < 4; ++r) ss[r] += __shfl_xor(ss[r], m2);
#pragma unroll
      for (int r = 0; r < 4; ++r) {
        int row = row0 + mi * 16 + lg * 4 + r;
        float inv = rsqrtf(ss[r] * 0.015625f + 1e-6f);
        float v0 = acc[mi][0][r] * inv * gam[0];
        float v1 = acc[mi][1][r] * inv * gam[1];
        float v2 = acc[mi][2][r] * inv * gam[2];
        float v3 = acc[mi][3][r] * inv * gam[3];
        int2 pp = posv[row];
        float sx, cx, sy, cy;
        __sincosf((float)pp.x * invf, &sx, &cx);
        __sincosf((float)pp.y * invf, &sy, &cy);
        float o0 = v0 * cx - v1 * sx, o1 = v1 * cx + v0 * sx;
        float o2 = v2 * cy - v3 * sy, o3 = v3 * cy + v2 * sy;
        int s = row & 1023, bb = row >> 10;
        short* base = dst + ((size_t)((bb * nh + h) * 1024 + s)) * 64;
        base[lr]      = f2bf(o0);
        base[lr + 16] = f2bf(o1);
        base[lr + 32] = f2bf(o2);
        base[lr + 48] = f2bf(o3);
      }
    }
  } else {
    int hk = g - 24;
#pragma unroll
    for (int mi = 0; mi < 4; ++mi) {
      f32x4 ss = acc[mi][0] * acc[mi][0];
#pragma unroll
      for (int ni = 1; ni < 4; ++ni) ss += acc[mi][ni] * acc[mi][ni];
#pragma unroll
      for (int m2 = 1; m2 < 16; m2 <<= 1)
#pragma unroll
        for (int r = 0; r < 4; ++r) ss[r] += __shfl_xor(ss[r], m2);
      f32x4 inv;
#pragma unroll
      for (int r = 0; r < 4; ++r) inv[r] = rsqrtf(ss[r] * 0.015625f + 1e-6f);
      int row = row0 + mi * 16 + lg * 4;
      int s0 = row & 1023, bb = row >> 10;
      int kv = s0 & 63, c = kv >> 3, hb = (kv >> 2) & 1;
      int sp = (s0 & ~63) | (((c & 6) | hb) << 3) | ((c & 1) << 2);
#pragma unroll
      for (int ni = 0; ni < 4; ++ni) {
        short4 sv;
        sv.x = f2bf(acc[mi][ni][0] * inv[0]);
        sv.y = f2bf(acc[mi][ni][1] * inv[1]);
        sv.z = f2bf(acc[mi][ni][2] * inv[2]);
        sv.w = f2bf(acc[mi][ni][3] * inv[3]);
        int d = ni * 16 + lr;
        *(short4*)&Vt[((size_t)((bb * 8 + hk) * 64 + d)) * 1024 + sp] = sv;
      }
    }
  }
}

// ------- 128x64-tile GEMM (out-proj), BK=32 dbuf, counted-vmcnt pipeline -------
__global__ __launch_bounds__(256) void gemm_bf16_bn64(
    const short* __restrict__ A, const short* __restrict__ BT,
    float* __restrict__ C, int M, int N, int K) {
  __shared__ short As[2][128 * 32];
  __shared__ short Bs[2][64 * 32];
  int wg = blockIdx.x + gridDim.x * blockIdx.y;      // nwg = 512
  int lid = (wg & 7) * 64 + (wg >> 3);
  int m0 = (lid & 31) * 128, n0 = (lid >> 5) * 64;
  int t = threadIdx.x;
  int w = t >> 6, lane = t & 63;
  int lr = lane & 15, lg = lane >> 4;

  f32x4 acc[2][4] = {};

  auto STAGE = [&](int buf, int k0) {
#pragma unroll
    for (int i = 0; i < 2; ++i) {
      int q = t + 256 * i;
      int row = q >> 2, c = q & 3;
      gload_lds16(A + (size_t)(m0 + row) * K + k0 + c * 8, &As[buf][q * 8]);
    }
    {
      int row = t >> 2, c = t & 3;       // 256 B-chunks
      gload_lds16(BT + (size_t)(n0 + row) * K + k0 + c * 8, &Bs[buf][t * 8]);
    }
  };

  auto COMPUTE = [&](int buf) {
    short8 af[2], bf[4];
#pragma unroll
    for (int mi = 0; mi < 2; ++mi)
      af[mi] = *(const short8*)&As[buf][(w * 32 + mi * 16 + lr) * 32 + lg * 8];
#pragma unroll
    for (int ni = 0; ni < 4; ++ni)
      bf[ni] = *(const short8*)&Bs[buf][(ni * 16 + lr) * 32 + lg * 8];
    __builtin_amdgcn_s_setprio(1);
#pragma unroll
    for (int mi = 0; mi < 2; ++mi)
#pragma unroll
      for (int ni = 0; ni < 4; ++ni)
        acc[mi][ni] = MFMA16(af[mi], bf[ni], acc[mi][ni]);
    __builtin_amdgcn_s_setprio(0);
  };

  STAGE(0, 0);
  int cur = 0;
  for (int kt = 0; kt < 31; ++kt) {
    STAGE(cur ^ 1, (kt + 1) * 32);
    asm volatile("s_waitcnt vmcnt(3)" ::: "memory");   // tile kt staged; kt+1 in flight
    __builtin_amdgcn_s_barrier();
    __builtin_amdgcn_sched_barrier(0);
    COMPUTE(cur);
    __builtin_amdgcn_sched_barrier(0);
    __builtin_amdgcn_s_barrier();
    cur ^= 1;
  }
  asm volatile("s_waitcnt vmcnt(0)" ::: "memory");
  __builtin_amdgcn_s_barrier();
  COMPUTE(cur);

#pragma unroll
  for (int mi = 0; mi < 2; ++mi)
#pragma unroll
    for (int ni = 0; ni < 4; ++ni) {
      int row = m0 + w * 32 + mi * 16 + lg * 4;
      int col = n0 + ni * 16 + lr;
#pragma unroll
      for (int r = 0; r < 4; ++r)
        C[(size_t)(row + r) * N + col] = acc[mi][ni][r];
    }
}

// ------------- attention v14 (best measured ~34 us; v15/v16/v17 all regressed) -------------
// grid 1024 = B*H*(S/64). Block = 64 q rows, 4 waves (qw,kw): qw owns 32 q-rows,
// kw owns one 512-kv half (8 tiles of 64). K and V DMA-staged, double-buffered;
// counted vmcnt(8) keeps next tile's 8 loads in flight across the barrier.
__global__ __launch_bounds__(256, 2) void attn_kernel(
    const short* __restrict__ Qp, const short* __restrict__ Kp,
    const short* __restrict__ Vt, short* __restrict__ attn) {
  __shared__ char smem[65536];          // [kw][buf] K (32KB) then V (32KB); merge aliases
  __shared__ float lsl[2][32][2];       // kw=1 lsum partials [qw][l31][hh]
  int wg = blockIdx.x;
  int xcd = wg & 7, slot = wg >> 3;        // 0..127
  int group = xcd * 8 + (slot >> 4);       // 0..63 = (b,h)
  int qblk = slot & 15;
  int b = group >> 4, h = group & 15;
  int hk = h >> 1;
  int t = threadIdx.x;                     // 0..255
  int w = t >> 6, lane = t & 63;
  int qw = w >> 1, kw = w & 1;
  int l31 = lane & 31, hh = lane >> 5;
  int xr = l31 & 7;
  int q0 = qblk * 64 + qw * 32;

  const short* Qb = Qp + ((size_t)(b * 16 + h) * 1024) * 64;
  const short* Kb = Kp + ((size_t)(b * 8 + hk) * 1024) * 64;
  const short* Vb = Vt + ((size_t)(b * 8 + hk) * 64) * 1024;

  short8 qf[4];
#pragma unroll
  for (int dk = 0; dk < 4; ++dk)
    qf[dk] = *(const short8*)&Qb[(q0 + l31) * 64 + dk * 16 + hh * 8];

  f32x16 acc[2] = {};   // [db2]: out^T[d=db2*32+(r&3)+8*(r>>2)+4hh][q=q0+l31]
  f32x4 lsumv = {};

  auto KsB = [&](int buf) { return (short*)(smem + (size_t)(kw * 2 + buf) * 8192); };
  auto VsB = [&](int buf) { return (short*)(smem + 32768 + (size_t)(kw * 2 + buf) * 8192); };

  auto STAGE = [&](int buf, int kt) {
    int kv0 = kw * 512 + kt * 64;
    short* ksb = KsB(buf);
    short* vsb = VsB(buf);
#pragma unroll
    for (int i = 0; i < 4; ++i) {
      int c = i * 128 + qw * 64 + lane;       // 512 chunks over 2 qw-waves x 4 i
      int kv = c >> 3, cd = c & 7, cs = cd ^ (kv & 7);
      gload_lds16(Kb + (size_t)(kv0 + kv) * 64 + cs * 8, &ksb[c * 8]);
    }
#pragma unroll
    for (int i = 0; i < 4; ++i) {
      int c = i * 128 + qw * 64 + lane;
      int d = c >> 3, bi = c & 7, bs = bi ^ (d & 7);
      gload_lds16(Vb + (size_t)d * 1024 + kv0 + bs * 8, &vsb[c * 8]);
    }
  };

  auto COMPUTE = [&](int buf) {
    const short* ksb = KsB(buf);
    const short* vsb = VsB(buf);
#pragma unroll
    for (int kvb2 = 0; kvb2 < 2; ++kvb2) {
      short8 kf[4];
#pragma unroll
      for (int dk = 0; dk < 4; ++dk)
        kf[dk] = *(const short8*)&ksb[(kvb2 * 32 + l31) * 64 + ((dk * 2 + hh) ^ xr) * 8];
      f32x16 sv = {};
      __builtin_amdgcn_s_setprio(1);
#pragma unroll
      for (int dk = 0; dk < 4; ++dk) sv = MFMA32(kf[dk], qf[dk], sv);
      __builtin_amdgcn_s_setprio(0);
      short8 vf[4];
#pragma unroll
      for (int kvc = 0; kvc < 2; ++kvc)
#pragma unroll
        for (int db2 = 0; db2 < 2; ++db2)
          vf[kvc * 2 + db2] = *(const short8*)
              &vsb[(db2 * 32 + l31) * 64 + (((kvb2 * 4 + kvc * 2 + hh) ^ xr)) * 8];
      float p[16];
#pragma unroll
      for (int r = 0; r < 16; ++r) p[r] = fexp2(sv[r]);
#pragma unroll
      for (int r = 0; r < 16; r += 4) {
        lsumv[0] += p[r]; lsumv[1] += p[r + 1];
        lsumv[2] += p[r + 2]; lsumv[3] += p[r + 3];
      }
      uint32_t pk8[8];
#pragma unroll
      for (int j = 0; j < 8; ++j) pk8[j] = pack_bf2(p[2 * j], p[2 * j + 1]);
#pragma unroll
      for (int kvc = 0; kvc < 2; ++kvc) {
        union { uint32_t u[4]; short8 s; } pb;
#pragma unroll
        for (int j = 0; j < 4; ++j) pb.u[j] = pk8[kvc * 4 + j];
        __builtin_amdgcn_s_setprio(1);
#pragma unroll
        for (int db2 = 0; db2 < 2; ++db2)
          acc[db2] = MFMA32(vf[kvc * 2 + db2], pb.s, acc[db2]);
        __builtin_amdgcn_s_setprio(0);
      }
    }
  };

  STAGE(0, 0);
  int cur = 0;
  for (int kt = 0; kt < 7; ++kt) {
    STAGE(cur ^ 1, kt + 1);
    asm volatile("s_waitcnt vmcnt(8)" ::: "memory");   // this wave's tile kt ready
    __builtin_amdgcn_s_barrier();
    __builtin_amdgcn_sched_barrier(0);
    COMPUTE(cur);
    __builtin_amdgcn_sched_barrier(0);
    __builtin_amdgcn_s_barrier();                      // qw-pair done reading buf
    cur ^= 1;
  }
  asm volatile("s_waitcnt vmcnt(0)" ::: "memory");
  __builtin_amdgcn_s_barrier();
  COMPUTE(cur);

  // ---- merge the two kv-halves (pure sums; no-max softmax) ----
  float lsum = (lsumv[0] + lsumv[1]) + (lsumv[2] + lsumv[3]);
  __syncthreads();                      // all K/V reads done; smem reusable
  float* accl = (float*)smem;           // [qw][l31][hh][36] (pad 36, 16B-aligned)
  float* ab = accl + (((qw * 32 + l31) * 2 + hh) * 36);
  if (kw == 1) {
#pragma unroll
    for (int db2 = 0; db2 < 2; ++db2)
#pragma unroll
      for (int j4 = 0; j4 < 4; ++j4) {
        f32x4 sv4;
        sv4[0] = acc[db2][j4 * 4];
        sv4[1] = acc[db2][j4 * 4 + 1];
        sv4[2] = acc[db2][j4 * 4 + 2];
        sv4[3] = acc[db2][j4 * 4 + 3];
        *(f32x4*)&ab[db2 * 16 + j4 * 4] = sv4;
      }
    lsl[qw][l31][hh] = lsum;
  }
  __syncthreads();
  if (kw == 0) {
#pragma unroll
    for (int db2 = 0; db2 < 2; ++db2)
#pragma unroll
      for (int j4 = 0; j4 < 4; ++j4) {
        f32x4 o = *(const f32x4*)&ab[db2 * 16 + j4 * 4];
        acc[db2][j4 * 4]     += o[0];
        acc[db2][j4 * 4 + 1] += o[1];
        acc[db2][j4 * 4 + 2] += o[2];
        acc[db2][j4 * 4 + 3] += o[3];
      }
    lsum += lsl[qw][l31][hh];
    lsum += __shfl_xor(lsum, 32);
    float inv = 1.0f / lsum;
    short* orow = attn + ((size_t)(b * 1024 + q0 + l31)) * 1024 + h * 64;
#pragma unroll
    for (int db2 = 0; db2 < 2; ++db2)
#pragma unroll
      for (int g2 = 0; g2 < 4; ++g2) {
        int d0 = db2 * 32 + g2 * 8 + 4 * hh;
        uint32_t w0 = pack_bf2(acc[db2][g2 * 4 + 0] * inv, acc[db2][g2 * 4 + 1] * inv);
        uint32_t w1 = pack_bf2(acc[db2][g2 * 4 + 2] * inv, acc[db2][g2 * 4 + 3] * inv);
        *(uint2*)&orow[d0] = make_uint2(w0, w1);
      }
  }
}

extern "C" void kernel_launch(void* const* d_in, const int* in_sizes, int n_in,
                              void* d_out, int out_size, void* d_ws, size_t ws_size,
                              hipStream_t stream) {
  const float* X  = (const float*)d_in[0];
  const float* Wq = (const float*)d_in[1];
  const float* Wk = (const float*)d_in[2];
  const float* Wv = (const float*)d_in[3];
  const float* Wo = (const float*)d_in[4];
  const float* qg = (const float*)d_in[5];
  const float* kg = (const float*)d_in[6];
  const int* pos  = (const int*)d_in[7];
  float* out = (float*)d_out;

  char* ws = (char*)d_ws;
  short* XB    = (short*)(ws);                       // 8 MB  X bf16
  short* WTQKV = (short*)(ws + ((size_t)8 << 20));   // 4 MB  [Wq^T;Wk^T;Wv^T]
  short* WOT   = (short*)(ws + ((size_t)12 << 20));  // 2 MB  Wo^T
  short* QP    = (short*)(ws + ((size_t)14 << 20));  // 8 MB
  short* KP    = (short*)(ws + ((size_t)22 << 20));  // 4 MB
  short* VT    = (short*)(ws + ((size_t)26 << 20));  // 4 MB
  short* ATT   = (short*)(ws + ((size_t)30 << 20));  // 8 MB -> 38 MB total

  prepass_kernel<<<4096 + 3072, 256, 0, stream>>>(X, Wq, Wk, Wv, Wo, XB, WTQKV, WOT);
  gemm_qkv_fused<<<dim3(32, 16), 256, 0, stream>>>(XB, WTQKV, qg, kg, pos, QP, KP, VT);
  attn_kernel<<<1024, 256, 0, stream>>>(QP, KP, VT, ATT);
  gemm_bf16_bn64<<<dim3(32, 16), 256, 0, stream>>>(ATT, WOT, out, 4096, 1024, 1024);
}